// Round 9
// baseline (513.169 us; speedup 1.0000x reference)
//
#include <hip/hip_runtime.h>

#define N_TOT   500000
#define M_Q     1024
#define QB      16
#define NSPLIT  16
#define CAND_MAX 4096

#define CROWS       16
#define NTILES      (N_TOT / CROWS)         // 31250
#define ARGMIN_BLKS 1024                    // 64 query-tiles x 16 N-splits
#define HIST_BLKS   32
#define USAGE_BLKS  64
#define COLL_BLKS   64
#define HIST_CHUNK  (N_TOT / HIST_BLKS)     // 15625

// block-index map (waiters are few: 66 << resident capacity => deadlock-free
// under ANY dispatch order; order below only helps latency)
#define B_HIST0     ARGMIN_BLKS                      // 1024
#define B_USAGE0    (B_HIST0 + HIST_BLKS)            // 1056
#define B_SCANV     (B_USAGE0 + USAGE_BLKS)          // 1120
#define B_COLL0     (B_SCANV + 1)                    // 1121
#define B_FINAL     (B_COLL0 + COLL_BLKS)            // 1185
#define B_COPY0     (B_FINAL + 1)                    // 1186
#define TOTAL_BLKS  (B_COPY0 + NTILES)               // 32436

#define TILE_F      (CROWS * 259)                    // 4144 floats (16B-aligned)

static const unsigned OUT_ROWS  = 259u * (unsigned)N_TOT;     // 129,500,000
static const unsigned OUT_USAGE = OUT_ROWS;
static const unsigned OUT_IDX   = OUT_ROWS + (unsigned)N_TOT; // 130,000,000

// ---- ws layout (bytes) ----
#define WS_PARTKEY 0                 // M*NSPLIT f32 = 65536
#define WS_PARTIDX 65536             // M*NSPLIT i32 = 65536
#define WS_HISTP   131072            // 32*1024 i32  = 131072
#define WS_V       262144            // 1 i32
#define WS_CNT     262148            // 1 i32
#define WS_FLAGS   262176            // 8 i32 (zeroed by k_init each launch)
#define WS_KEYS    262208            // CAND_MAX u32 = 16384

#define F_HIST 0
#define F_SCN  1
#define F_COL  2
#define F_ARG  3
#define F_USG  4

__device__ __forceinline__ void spin_until(int* f, int want) {
    while (atomicAdd(f, 0) < want) __builtin_amdgcn_s_sleep(16);
    __threadfence();   // acquire: invalidate L1 before reading producer data
}

__global__ void k_init(int* flags, int* cnt) {
    if (threadIdx.x < 8) flags[threadIdx.x] = 0;
    if (threadIdx.x == 8) *cnt = 0;
}

// =========== ONE KERNEL: copy || argmin || hist || usage || scanV/collect/final ====
__global__ __launch_bounds__(256, 6) void k_one(
    const float* __restrict__ pts,  const float* __restrict__ mpts,
    const float* __restrict__ mdesc, const int* __restrict__ usage,
    float* __restrict__ out,
    float* __restrict__ partKey, int* __restrict__ partIdx,
    int* __restrict__ histPart, int* __restrict__ Vp, int* __restrict__ cnt,
    int* __restrict__ flags, unsigned* __restrict__ keysG)
{
    __shared__ int smem[4432];            // 17728 B union across roles
    const int b   = blockIdx.x;
    const int tid = threadIdx.x;

    if (b >= B_COPY0) {
        // ------- row-copy role (R4 champion, byte-identical): LDS-staged, aligned ----
        const int cb = b - B_COPY0;           // 0..31249
        const int n0 = cb * CROWS;
        float* L = (float*)smem;

        const float4* src = (const float4*)(mdesc + (size_t)n0 * 256);
#pragma unroll
        for (int it = 0; it < 4; it++) {
            int g = tid + it * 256;           // 0..1023 float4s
            float4 v = src[g];
            int r = g >> 6;
            int c = (g & 63) << 2;
            float* d = L + r * 259 + 3 + c;
            d[0] = v.x; d[1] = v.y; d[2] = v.z; d[3] = v.w;
        }
        if (tid < CROWS * 3) {
            int r = tid / 3, c = tid - r * 3;
            L[r * 259 + c] = mpts[(size_t)n0 * 3 + tid];
        }
        __syncthreads();

        float4* dst4 = (float4*)(out + (size_t)cb * TILE_F);
        const float4* s4 = (const float4*)L;
#pragma unroll
        for (int it = 0; it < 5; it++) {
            int g = tid + it * 256;
            if (g < TILE_F / 4) dst4[g] = s4[g];
        }
    } else if (b < ARGMIN_BLKS) {
        // ---------------- argmin role (math identical since R1: absmax 0) ----------
        const int qb = b & 63;
        const int ns = b >> 6;
        const int qbase = qb * QB;
        const int chunk = N_TOT / NSPLIT;     // 31250
        const int n0 = ns * chunk;
        const int n1 = n0 + chunk;

        float* qs = (float*)smem;             // 48 floats
        float* wk = (float*)smem + 64;        // [4][16]
        int*   wi = smem + 192;               // [4][16]
        if (tid < QB * 3) qs[tid] = pts[qbase * 3 + tid];
        __syncthreads();

        float qx[QB], qy[QB], qz[QB];
#pragma unroll
        for (int i = 0; i < QB; i++) { qx[i] = qs[3*i]; qy[i] = qs[3*i+1]; qz[i] = qs[3*i+2]; }

        float bk[QB]; int bi[QB];
#pragma unroll
        for (int i = 0; i < QB; i++) { bk[i] = INFINITY; bi[i] = 0x7fffffff; }

        for (int n = n0 + tid; n < n1; n += 256) {
            float x = mpts[3*n+0], y = mpts[3*n+1], z = mpts[3*n+2];
            float h = 0.5f * (x*x + y*y + z*z);
#pragma unroll
            for (int i = 0; i < QB; i++) {
                float key = h - x*qx[i] - y*qy[i] - z*qz[i];
                bool lt = key < bk[i];        // strict < + ascending n => first-min kept
                bk[i] = lt ? key : bk[i];
                bi[i] = lt ? n   : bi[i];
            }
        }

        const int lane = tid & 63;
        const int wv   = tid >> 6;
#pragma unroll
        for (int off = 32; off > 0; off >>= 1) {
#pragma unroll
            for (int i = 0; i < QB; i++) {
                float ok = __shfl_down(bk[i], off, 64);
                int   oi = __shfl_down(bi[i], off, 64);
                if (ok < bk[i] || (ok == bk[i] && oi < bi[i])) { bk[i] = ok; bi[i] = oi; }
            }
        }
        if (lane == 0) {
#pragma unroll
            for (int i = 0; i < QB; i++) { wk[wv*QB + i] = bk[i]; wi[wv*QB + i] = bi[i]; }
        }
        __syncthreads();
        if (tid < QB) {
            float k = wk[tid]; int ix = wi[tid];
#pragma unroll
            for (int w = 1; w < 4; w++) {
                float ok = wk[w*QB + tid]; int oi = wi[w*QB + tid];
                if (ok < k || (ok == k && oi < ix)) { k = ok; ix = oi; }
            }
            partKey[(qbase + tid) * NSPLIT + ns] = k;
            partIdx[(qbase + tid) * NSPLIT + ns] = ix;
        }
        __threadfence();                      // release partials
        __syncthreads();
        if (tid == 0) atomicAdd(&flags[F_ARG], 1);
    } else if (b < B_USAGE0) {
        // ---------------- hist role: per-block partial histogram -------------------
        const int hb = b - B_HIST0;
        const int r0 = hb * HIST_CHUNK;
        const int r1 = r0 + HIST_CHUNK;
#pragma unroll
        for (int i = 0; i < 4; i++) smem[tid + i * 256] = 0;
        __syncthreads();
        for (int n = r0 + tid; n < r1; n += 256) {
            unsigned v = (unsigned)usage[n];
            if (v > 1023u) v = 1023u;
            atomicAdd(&smem[v], 1);
        }
        __syncthreads();
#pragma unroll
        for (int i = 0; i < 4; i++) {
            int bin = tid + i * 256;
            histPart[hb * 1024 + bin] = smem[bin];
        }
        __threadfence();
        __syncthreads();
        if (tid == 0) atomicAdd(&flags[F_HIST], 1);
    } else if (b < B_SCANV) {
        // ---------------- usage-as-float role (int4 -> float4) ---------------------
        const int ub = b - B_USAGE0;
        const int4* u4 = (const int4*)usage;
        float4* o4 = (float4*)(out + OUT_USAGE);
        const int TOT4 = N_TOT / 4;           // 125000
        for (int g = ub * 256 + tid; g < TOT4; g += USAGE_BLKS * 256) {
            int4 u = u4[g];
            o4[g] = make_float4((float)u.x, (float)u.y, (float)u.z, (float)u.w);
        }
        __threadfence();
        __syncthreads();
        if (tid == 0) atomicAdd(&flags[F_USG], 1);
    } else if (b == B_SCANV) {
        // ---------------- scanV: total hist, scan, cutoff V ------------------------
        if (tid == 0) spin_until(&flags[F_HIST], HIST_BLKS);
        __syncthreads();
        int h[4];
#pragma unroll
        for (int j = 0; j < 4; j++) {
            h[j] = 0;
            for (int bb = 0; bb < HIST_BLKS; bb++) h[j] += histPart[bb * 1024 + tid * 4 + j];
        }
        int lsum = h[0] + h[1] + h[2] + h[3];
        smem[tid] = lsum; __syncthreads();
        for (int off = 1; off < 256; off <<= 1) {
            int add = (tid >= off) ? smem[tid - off] : 0;
            __syncthreads();
            smem[tid] += add;
            __syncthreads();
        }
        int run = smem[tid] - lsum;           // exclusive count(usage < 4*tid)
#pragma unroll
        for (int j = 0; j < 4; j++) {
            int incl = run + h[j];
            if (run < M_Q && incl >= M_Q) {   // unique crossing bin
                atomicExch(Vp, tid * 4 + j);
                __threadfence();
            }
            run = incl;
        }
        __syncthreads();
        if (tid == 0) atomicAdd(&flags[F_SCN], 1);
    } else if (b < B_FINAL) {
        // ---------------- collect role: candidates usage <= V, unordered -----------
        const int rb = b - B_COLL0;           // 0..63
        if (tid == 0) {
            spin_until(&flags[F_SCN], 1);
            smem[0] = atomicAdd(Vp, 0);
        }
        __syncthreads();
        const int V = smem[0];
        for (int n = rb * 256 + tid; n < N_TOT; n += COLL_BLKS * 256) {
            int u = usage[n];
            if (u <= V) {
                int p = atomicAdd(cnt, 1);
                if (p < CAND_MAX) keysG[p] = ((unsigned)u << 19) | (unsigned)n;
            }
        }
        __threadfence();
        __syncthreads();
        if (tid == 0) atomicAdd(&flags[F_COL], 1);
    } else {
        // ---------------- final: sort, rank, idx out, usage bump -------------------
        unsigned* keys = (unsigned*)smem;     // [4096]
        int* sc     = smem + 4096;            // [256]
        int* s_misc = smem + 4400;
        if (tid == 0) {
            spin_until(&flags[F_ARG], ARGMIN_BLKS);
            spin_until(&flags[F_USG], USAGE_BLKS);
            spin_until(&flags[F_COL], COLL_BLKS);
            s_misc[0] = atomicAdd(cnt, 0);
        }
        __syncthreads();
        int C = s_misc[0]; if (C > CAND_MAX) C = CAND_MAX;
        int P2 = 1; while (P2 < C) P2 <<= 1;

        // per-thread 4 queries: reduce NSPLIT partials (ascending order: strict <)
        int   bi4[4], msk[4];
#pragma unroll
        for (int j = 0; j < 4; j++) {
            int q = tid * 4 + j;
            float bk = INFINITY; int ix = 0x7fffffff;
            for (int s = 0; s < NSPLIT; s++) {
                float k = partKey[q * NSPLIT + s];
                int   i = partIdx[q * NSPLIT + s];
                if (k < bk) { bk = k; ix = i; }
            }
            float px = pts[3*q], py = pts[3*q+1], pz = pts[3*q+2];
            float d2 = px*px + py*py + pz*pz + 2.0f * bk;
            msk[j] = (d2 > 1e-6f) ? 1 : 0;    // sqrt(max(d2,1e-12)) > 1e-3
            bi4[j] = ix;
        }

        // load candidates, pad to P2
        for (int p = tid; p < P2; p += 256) keys[p] = (p < C) ? keysG[p] : 0xFFFFFFFFu;
        __syncthreads();

        // bitonic sort ascending -> (usage asc, index asc) == lax.top_k order
        for (int k2 = 2; k2 <= P2; k2 <<= 1) {
            for (int j = k2 >> 1; j > 0; j >>= 1) {
                for (int i = tid; i < P2; i += 256) {
                    int ixj = i ^ j;
                    if (ixj > i) {
                        unsigned a = keys[i], bb2 = keys[ixj];
                        bool up = ((i & k2) == 0);
                        if ((a > bb2) == up) { keys[i] = bb2; keys[ixj] = a; }
                    }
                }
                __syncthreads();
            }
        }

        // rank = cumsum(mask)-1 over queries in order
        int lsum = msk[0] + msk[1] + msk[2] + msk[3];
        sc[tid] = lsum; __syncthreads();
        for (int off = 1; off < 256; off <<= 1) {
            int add = (tid >= off) ? sc[tid - off] : 0;
            __syncthreads();
            sc[tid] += add;
            __syncthreads();
        }
        int run = sc[tid] - lsum;
#pragma unroll
        for (int j = 0; j < 4; j++) {
            int q = tid * 4 + j;
            run += msk[j];
            int idx = msk[j] ? (int)(keys[run - 1] & 0x7FFFFu) : bi4[j];
            out[(size_t)OUT_IDX + (size_t)q] = (float)idx;
            atomicAdd(out + OUT_USAGE + idx, 1.0f);   // after usage role (flag-gated)
        }
    }
}

extern "C" void kernel_launch(void* const* d_in, const int* in_sizes, int n_in,
                              void* d_out, int out_size, void* d_ws, size_t ws_size,
                              hipStream_t stream)
{
    (void)in_sizes; (void)n_in; (void)out_size; (void)ws_size;
    const float* pts   = (const float*)d_in[0];
    const float* mpts  = (const float*)d_in[2];
    const float* mdesc = (const float*)d_in[3];
    const int*   usage = (const int*)d_in[4];
    float* out = (float*)d_out;

    char* ws = (char*)d_ws;
    float*    partKey  = (float*)(ws + WS_PARTKEY);
    int*      partIdx  = (int*)(ws + WS_PARTIDX);
    int*      histPart = (int*)(ws + WS_HISTP);
    int*      Vp       = (int*)(ws + WS_V);
    int*      cnt      = (int*)(ws + WS_CNT);
    int*      flags    = (int*)(ws + WS_FLAGS);
    unsigned* keysG    = (unsigned*)(ws + WS_KEYS);

    k_init<<<1, 64, 0, stream>>>(flags, cnt);
    k_one<<<TOTAL_BLKS, 256, 0, stream>>>(pts, mpts, mdesc, usage, out,
                                          partKey, partIdx, histPart,
                                          Vp, cnt, flags, keysG);
}

// Round 10
// 496.325 us; speedup vs baseline: 1.0339x; 1.0339x over previous
//
#include <hip/hip_runtime.h>

#define N_TOT   500000
#define M_Q     1024
#define QB      16
#define NSPLIT  16
#define CAND_MAX 4096

#define CROWS       16
#define NTILES      (N_TOT / CROWS)         // 31250
#define ARGMIN_BLKS 1024                    // 64 query-tiles x 16 N-splits
#define HIST_BLKS   32
#define USAGE_BLKS  64
#define COLL_BLKS   64
#define HIST_CHUNK  (N_TOT / HIST_BLKS)     // 15625

// block-index map (waiters are few: 66 << resident capacity => deadlock-free
// under ANY dispatch order; order below only helps latency)
#define B_HIST0     ARGMIN_BLKS                      // 1024
#define B_USAGE0    (B_HIST0 + HIST_BLKS)            // 1056
#define B_SCANV     (B_USAGE0 + USAGE_BLKS)          // 1120
#define B_COLL0     (B_SCANV + 1)                    // 1121
#define B_FINAL     (B_COLL0 + COLL_BLKS)            // 1185
#define B_COPY0     (B_FINAL + 1)                    // 1186
#define TOTAL_BLKS  (B_COPY0 + NTILES)               // 32436

#define TILE_F      (CROWS * 259)                    // 4144 floats (16B-aligned)

static const unsigned OUT_ROWS  = 259u * (unsigned)N_TOT;     // 129,500,000
static const unsigned OUT_USAGE = OUT_ROWS;
static const unsigned OUT_IDX   = OUT_ROWS + (unsigned)N_TOT; // 130,000,000

// ---- ws layout (bytes) ----
#define WS_PARTKEY 0                 // M*NSPLIT f32 = 65536
#define WS_PARTIDX 65536             // M*NSPLIT i32 = 65536
#define WS_HISTP   131072            // 32*1024 i32  = 131072
#define WS_V       262144            // 1 i32
#define WS_CNT     262148            // 1 i32
#define WS_FLAGS   262176            // 8 i32 (zeroed by k_init each launch)
#define WS_KEYS    262208            // CAND_MAX u32 = 16384

#define F_HIST 0
#define F_SCN  1
#define F_COL  2
#define F_ARG  3
#define F_USG  4

__device__ __forceinline__ void spin_until(int* f, int want) {
    while (atomicAdd(f, 0) < want) __builtin_amdgcn_s_sleep(16);
    __threadfence();   // acquire: see producer data
}

__global__ void k_init(int* flags, int* cnt) {
    if (threadIdx.x < 8) flags[threadIdx.x] = 0;
    if (threadIdx.x == 8) *cnt = 0;
}

// =========== ONE KERNEL: copy || argmin || hist || usage || scanV/collect/final ====
// NOTE: no min-waves occupancy bound — R9's (256,6) register-throttled argmin
// (VGPR 56->40, spill to scratch, FETCH +120MB). Compiler picks VGPRs freely.
__global__ __launch_bounds__(256) void k_one(
    const float* __restrict__ pts,  const float* __restrict__ mpts,
    const float* __restrict__ mdesc, const int* __restrict__ usage,
    float* __restrict__ out,
    float* __restrict__ partKey, int* __restrict__ partIdx,
    int* __restrict__ histPart, int* __restrict__ Vp, int* __restrict__ cnt,
    int* __restrict__ flags, unsigned* __restrict__ keysG)
{
    __shared__ int smem[4432];            // 17728 B union across roles
    const int b   = blockIdx.x;
    const int tid = threadIdx.x;

    if (b >= B_COPY0) {
        // ------- row-copy role (R4 champion, byte-identical): LDS-staged, aligned ----
        const int cb = b - B_COPY0;           // 0..31249
        const int n0 = cb * CROWS;
        float* L = (float*)smem;

        const float4* src = (const float4*)(mdesc + (size_t)n0 * 256);
#pragma unroll
        for (int it = 0; it < 4; it++) {
            int g = tid + it * 256;           // 0..1023 float4s
            float4 v = src[g];
            int r = g >> 6;
            int c = (g & 63) << 2;
            float* d = L + r * 259 + 3 + c;
            d[0] = v.x; d[1] = v.y; d[2] = v.z; d[3] = v.w;
        }
        if (tid < CROWS * 3) {
            int r = tid / 3, c = tid - r * 3;
            L[r * 259 + c] = mpts[(size_t)n0 * 3 + tid];
        }
        __syncthreads();

        float4* dst4 = (float4*)(out + (size_t)cb * TILE_F);
        const float4* s4 = (const float4*)L;
#pragma unroll
        for (int it = 0; it < 5; it++) {
            int g = tid + it * 256;
            if (g < TILE_F / 4) dst4[g] = s4[g];
        }
    } else if (b < ARGMIN_BLKS) {
        // ---------------- argmin role (math identical since R1: absmax 0) ----------
        const int qb = b & 63;
        const int ns = b >> 6;
        const int qbase = qb * QB;
        const int chunk = N_TOT / NSPLIT;     // 31250
        const int n0 = ns * chunk;
        const int n1 = n0 + chunk;

        float* qs = (float*)smem;             // 48 floats
        float* wk = (float*)smem + 64;        // [4][16]
        int*   wi = smem + 192;               // [4][16]
        if (tid < QB * 3) qs[tid] = pts[qbase * 3 + tid];
        __syncthreads();

        float qx[QB], qy[QB], qz[QB];
#pragma unroll
        for (int i = 0; i < QB; i++) { qx[i] = qs[3*i]; qy[i] = qs[3*i+1]; qz[i] = qs[3*i+2]; }

        float bk[QB]; int bi[QB];
#pragma unroll
        for (int i = 0; i < QB; i++) { bk[i] = INFINITY; bi[i] = 0x7fffffff; }

        for (int n = n0 + tid; n < n1; n += 256) {
            float x = mpts[3*n+0], y = mpts[3*n+1], z = mpts[3*n+2];
            float h = 0.5f * (x*x + y*y + z*z);
#pragma unroll
            for (int i = 0; i < QB; i++) {
                float key = h - x*qx[i] - y*qy[i] - z*qz[i];
                bool lt = key < bk[i];        // strict < + ascending n => first-min kept
                bk[i] = lt ? key : bk[i];
                bi[i] = lt ? n   : bi[i];
            }
        }

        const int lane = tid & 63;
        const int wv   = tid >> 6;
#pragma unroll
        for (int off = 32; off > 0; off >>= 1) {
#pragma unroll
            for (int i = 0; i < QB; i++) {
                float ok = __shfl_down(bk[i], off, 64);
                int   oi = __shfl_down(bi[i], off, 64);
                if (ok < bk[i] || (ok == bk[i] && oi < bi[i])) { bk[i] = ok; bi[i] = oi; }
            }
        }
        if (lane == 0) {
#pragma unroll
            for (int i = 0; i < QB; i++) { wk[wv*QB + i] = bk[i]; wi[wv*QB + i] = bi[i]; }
        }
        __syncthreads();
        if (tid < QB) {
            float k = wk[tid]; int ix = wi[tid];
#pragma unroll
            for (int w = 1; w < 4; w++) {
                float ok = wk[w*QB + tid]; int oi = wi[w*QB + tid];
                if (ok < k || (ok == k && oi < ix)) { k = ok; ix = oi; }
            }
            partKey[(qbase + tid) * NSPLIT + ns] = k;
            partIdx[(qbase + tid) * NSPLIT + ns] = ix;
        }
        __threadfence();                      // release partials
        __syncthreads();
        if (tid == 0) atomicAdd(&flags[F_ARG], 1);
    } else if (b < B_USAGE0) {
        // ---------------- hist role: per-block partial histogram -------------------
        const int hb = b - B_HIST0;
        const int r0 = hb * HIST_CHUNK;
        const int r1 = r0 + HIST_CHUNK;
#pragma unroll
        for (int i = 0; i < 4; i++) smem[tid + i * 256] = 0;
        __syncthreads();
        for (int n = r0 + tid; n < r1; n += 256) {
            unsigned v = (unsigned)usage[n];
            if (v > 1023u) v = 1023u;
            atomicAdd(&smem[v], 1);
        }
        __syncthreads();
#pragma unroll
        for (int i = 0; i < 4; i++) {
            int bin = tid + i * 256;
            histPart[hb * 1024 + bin] = smem[bin];
        }
        __threadfence();
        __syncthreads();
        if (tid == 0) atomicAdd(&flags[F_HIST], 1);
    } else if (b < B_SCANV) {
        // ---------------- usage-as-float role (int4 -> float4) ---------------------
        const int ub = b - B_USAGE0;
        const int4* u4 = (const int4*)usage;
        float4* o4 = (float4*)(out + OUT_USAGE);
        const int TOT4 = N_TOT / 4;           // 125000
        for (int g = ub * 256 + tid; g < TOT4; g += USAGE_BLKS * 256) {
            int4 u = u4[g];
            o4[g] = make_float4((float)u.x, (float)u.y, (float)u.z, (float)u.w);
        }
        __threadfence();
        __syncthreads();
        if (tid == 0) atomicAdd(&flags[F_USG], 1);
    } else if (b == B_SCANV) {
        // ---------------- scanV: total hist, scan, cutoff V ------------------------
        if (tid == 0) spin_until(&flags[F_HIST], HIST_BLKS);
        __syncthreads();
        int h[4];
#pragma unroll
        for (int j = 0; j < 4; j++) {
            h[j] = 0;
            for (int bb = 0; bb < HIST_BLKS; bb++) h[j] += histPart[bb * 1024 + tid * 4 + j];
        }
        int lsum = h[0] + h[1] + h[2] + h[3];
        smem[tid] = lsum; __syncthreads();
        for (int off = 1; off < 256; off <<= 1) {
            int add = (tid >= off) ? smem[tid - off] : 0;
            __syncthreads();
            smem[tid] += add;
            __syncthreads();
        }
        int run = smem[tid] - lsum;           // exclusive count(usage < 4*tid)
#pragma unroll
        for (int j = 0; j < 4; j++) {
            int incl = run + h[j];
            if (run < M_Q && incl >= M_Q) {   // unique crossing bin
                atomicExch(Vp, tid * 4 + j);
                __threadfence();
            }
            run = incl;
        }
        __syncthreads();
        if (tid == 0) atomicAdd(&flags[F_SCN], 1);
    } else if (b < B_FINAL) {
        // ---------------- collect role: candidates usage <= V, unordered -----------
        const int rb = b - B_COLL0;           // 0..63
        if (tid == 0) {
            spin_until(&flags[F_SCN], 1);
            smem[0] = atomicAdd(Vp, 0);
        }
        __syncthreads();
        const int V = smem[0];
        for (int n = rb * 256 + tid; n < N_TOT; n += COLL_BLKS * 256) {
            int u = usage[n];
            if (u <= V) {
                int p = atomicAdd(cnt, 1);
                if (p < CAND_MAX) keysG[p] = ((unsigned)u << 19) | (unsigned)n;
            }
        }
        __threadfence();
        __syncthreads();
        if (tid == 0) atomicAdd(&flags[F_COL], 1);
    } else {
        // ---------------- final: sort, rank, idx out, usage bump -------------------
        unsigned* keys = (unsigned*)smem;     // [4096]
        int* sc     = smem + 4096;            // [256]
        int* s_misc = smem + 4400;
        if (tid == 0) {
            spin_until(&flags[F_ARG], ARGMIN_BLKS);
            spin_until(&flags[F_USG], USAGE_BLKS);
            spin_until(&flags[F_COL], COLL_BLKS);
            s_misc[0] = atomicAdd(cnt, 0);
        }
        __syncthreads();
        int C = s_misc[0]; if (C > CAND_MAX) C = CAND_MAX;
        int P2 = 1; while (P2 < C) P2 <<= 1;

        // per-thread 4 queries: reduce NSPLIT partials (ascending order: strict <)
        int   bi4[4], msk[4];
#pragma unroll
        for (int j = 0; j < 4; j++) {
            int q = tid * 4 + j;
            float bk = INFINITY; int ix = 0x7fffffff;
            for (int s = 0; s < NSPLIT; s++) {
                float k = partKey[q * NSPLIT + s];
                int   i = partIdx[q * NSPLIT + s];
                if (k < bk) { bk = k; ix = i; }
            }
            float px = pts[3*q], py = pts[3*q+1], pz = pts[3*q+2];
            float d2 = px*px + py*py + pz*pz + 2.0f * bk;
            msk[j] = (d2 > 1e-6f) ? 1 : 0;    // sqrt(max(d2,1e-12)) > 1e-3
            bi4[j] = ix;
        }

        // load candidates, pad to P2
        for (int p = tid; p < P2; p += 256) keys[p] = (p < C) ? keysG[p] : 0xFFFFFFFFu;
        __syncthreads();

        // bitonic sort ascending -> (usage asc, index asc) == lax.top_k order
        for (int k2 = 2; k2 <= P2; k2 <<= 1) {
            for (int j = k2 >> 1; j > 0; j >>= 1) {
                for (int i = tid; i < P2; i += 256) {
                    int ixj = i ^ j;
                    if (ixj > i) {
                        unsigned a = keys[i], bb2 = keys[ixj];
                        bool up = ((i & k2) == 0);
                        if ((a > bb2) == up) { keys[i] = bb2; keys[ixj] = a; }
                    }
                }
                __syncthreads();
            }
        }

        // rank = cumsum(mask)-1 over queries in order
        int lsum = msk[0] + msk[1] + msk[2] + msk[3];
        sc[tid] = lsum; __syncthreads();
        for (int off = 1; off < 256; off <<= 1) {
            int add = (tid >= off) ? sc[tid - off] : 0;
            __syncthreads();
            sc[tid] += add;
            __syncthreads();
        }
        int run = sc[tid] - lsum;
#pragma unroll
        for (int j = 0; j < 4; j++) {
            int q = tid * 4 + j;
            run += msk[j];
            int idx = msk[j] ? (int)(keys[run - 1] & 0x7FFFFu) : bi4[j];
            out[(size_t)OUT_IDX + (size_t)q] = (float)idx;
            atomicAdd(out + OUT_USAGE + idx, 1.0f);   // after usage role (flag-gated)
        }
    }
}

extern "C" void kernel_launch(void* const* d_in, const int* in_sizes, int n_in,
                              void* d_out, int out_size, void* d_ws, size_t ws_size,
                              hipStream_t stream)
{
    (void)in_sizes; (void)n_in; (void)out_size; (void)ws_size;
    const float* pts   = (const float*)d_in[0];
    const float* mpts  = (const float*)d_in[2];
    const float* mdesc = (const float*)d_in[3];
    const int*   usage = (const int*)d_in[4];
    float* out = (float*)d_out;

    char* ws = (char*)d_ws;
    float*    partKey  = (float*)(ws + WS_PARTKEY);
    int*      partIdx  = (int*)(ws + WS_PARTIDX);
    int*      histPart = (int*)(ws + WS_HISTP);
    int*      Vp       = (int*)(ws + WS_V);
    int*      cnt      = (int*)(ws + WS_CNT);
    int*      flags    = (int*)(ws + WS_FLAGS);
    unsigned* keysG    = (unsigned*)(ws + WS_KEYS);

    k_init<<<1, 64, 0, stream>>>(flags, cnt);
    k_one<<<TOTAL_BLKS, 256, 0, stream>>>(pts, mpts, mdesc, usage, out,
                                          partKey, partIdx, histPart,
                                          Vp, cnt, flags, keysG);
}

// Round 11
// 374.848 us; speedup vs baseline: 1.3690x; 1.3241x over previous
//
#include <hip/hip_runtime.h>

#define N_TOT   500000
#define M_Q     1024
#define QB      16
#define NSPLIT  16
#define CAND_MAX 4096

#define ARGMIN_BLKS 1024            // 64 query-tiles x 16 N-splits
#define HIST_BLKS   32
#define USAGE_BLKS  64
#define CROWS       16              // rows per copy tile
#define COPY_BLKS   (N_TOT / CROWS) // 31250
#define MEGA_BLKS   (ARGMIN_BLKS + HIST_BLKS + USAGE_BLKS + COPY_BLKS)
#define HIST_CHUNK  (N_TOT / HIST_BLKS)   // 15625
#define TILE_F      (CROWS * 259)         // 4144 floats (16B-aligned)

#define COLL_BLKS   64
#define TAIL_BLKS   (1 + COLL_BLKS)

static const unsigned OUT_ROWS  = 259u * (unsigned)N_TOT;     // 129,500,000
static const unsigned OUT_USAGE = OUT_ROWS;
static const unsigned OUT_IDX   = OUT_ROWS + (unsigned)N_TOT; // 130,000,000

// ---- ws layout (bytes) ----
#define WS_PARTKEY 0                 // M*NSPLIT f32 = 65536
#define WS_PARTIDX 65536             // M*NSPLIT i32 = 65536
#define WS_HISTP   131072            // 32*1024 i32  = 131072
#define WS_V       262144            // 1 i32
#define WS_CNT     262148            // 1 i32
#define WS_FLAGS   262176            // 8 i32 (zeroed by mega each call)
#define WS_KEYS    262208            // CAND_MAX u32

#define F_SCN  0
#define F_COL  1

typedef float f4v __attribute__((ext_vector_type(4)));

__device__ __forceinline__ void spin_until(int* f, int want) {
    while (atomicAdd(f, 0) < want) __builtin_amdgcn_s_sleep(16);
    __threadfence();   // acquire
}

// =====================  MEGA: argmin || hist || usage || row-copy  =================
// R4 champion structure byte-identical, except: (1) copy loads are nontemporal,
// (2) usage-role block 0 zeroes tail flags/cnt (visible at kernel boundary).
__global__ __launch_bounds__(256) void k_mega(
    const float* __restrict__ pts,  const float* __restrict__ mpts,
    const float* __restrict__ mdesc, const int* __restrict__ usage,
    float* __restrict__ out,
    float* __restrict__ partKey, int* __restrict__ partIdx,
    int* __restrict__ histPart, int* __restrict__ flags, int* __restrict__ cnt)
{
    __shared__ float smem[TILE_F];        // 16576 B, unioned across roles
    const int b   = blockIdx.x;
    const int tid = threadIdx.x;

    if (b < ARGMIN_BLKS) {
        // ---------------- argmin role (math identical since R1: absmax 0) ----------
        const int qb = b & 63;
        const int ns = b >> 6;
        const int qbase = qb * QB;
        const int chunk = N_TOT / NSPLIT;   // 31250
        const int n0 = ns * chunk;
        const int n1 = n0 + chunk;

        float* qs = smem;                   // 48 floats
        float* wk = smem + 64;              // [4][16]
        int*   wi = (int*)(smem + 192);     // [4][16]
        if (tid < QB * 3) qs[tid] = pts[qbase * 3 + tid];
        __syncthreads();

        float qx[QB], qy[QB], qz[QB];
#pragma unroll
        for (int i = 0; i < QB; i++) { qx[i] = qs[3*i]; qy[i] = qs[3*i+1]; qz[i] = qs[3*i+2]; }

        float bk[QB]; int bi[QB];
#pragma unroll
        for (int i = 0; i < QB; i++) { bk[i] = INFINITY; bi[i] = 0x7fffffff; }

        for (int n = n0 + tid; n < n1; n += 256) {
            float x = mpts[3*n+0], y = mpts[3*n+1], z = mpts[3*n+2];
            float h = 0.5f * (x*x + y*y + z*z);
#pragma unroll
            for (int i = 0; i < QB; i++) {
                float key = h - x*qx[i] - y*qy[i] - z*qz[i];
                bool lt = key < bk[i];      // strict < + ascending n => first-min kept
                bk[i] = lt ? key : bk[i];
                bi[i] = lt ? n   : bi[i];
            }
        }

        const int lane = tid & 63;
        const int wv   = tid >> 6;
#pragma unroll
        for (int off = 32; off > 0; off >>= 1) {
#pragma unroll
            for (int i = 0; i < QB; i++) {
                float ok = __shfl_down(bk[i], off, 64);
                int   oi = __shfl_down(bi[i], off, 64);
                if (ok < bk[i] || (ok == bk[i] && oi < bi[i])) { bk[i] = ok; bi[i] = oi; }
            }
        }
        if (lane == 0) {
#pragma unroll
            for (int i = 0; i < QB; i++) { wk[wv*QB + i] = bk[i]; wi[wv*QB + i] = bi[i]; }
        }
        __syncthreads();
        if (tid < QB) {
            float k = wk[tid]; int ix = wi[tid];
#pragma unroll
            for (int w = 1; w < 4; w++) {
                float ok = wk[w*QB + tid]; int oi = wi[w*QB + tid];
                if (ok < k || (ok == k && oi < ix)) { k = ok; ix = oi; }
            }
            partKey[(qbase + tid) * NSPLIT + ns] = k;
            partIdx[(qbase + tid) * NSPLIT + ns] = ix;
        }
    } else if (b < ARGMIN_BLKS + HIST_BLKS) {
        // ---------------- hist role: per-block partial histogram -------------------
        const int hb = b - ARGMIN_BLKS;
        const int r0 = hb * HIST_CHUNK;
        const int r1 = r0 + HIST_CHUNK;
        int* lh = (int*)smem;
#pragma unroll
        for (int i = 0; i < 4; i++) lh[tid + i * 256] = 0;
        __syncthreads();
        for (int n = r0 + tid; n < r1; n += 256) {
            unsigned v = (unsigned)usage[n];
            if (v > 1023u) v = 1023u;
            atomicAdd(&lh[v], 1);
        }
        __syncthreads();
#pragma unroll
        for (int i = 0; i < 4; i++) {
            int bin = tid + i * 256;
            histPart[hb * 1024 + bin] = lh[bin];
        }
    } else if (b < ARGMIN_BLKS + HIST_BLKS + USAGE_BLKS) {
        // ---------------- usage-as-float role (int4 -> float4) ---------------------
        const int ub = b - ARGMIN_BLKS - HIST_BLKS;
        if (ub == 0 && tid < 16) {          // zero tail state (kernel-boundary coherent)
            if (tid < 8) flags[tid] = 0;
            if (tid == 8) *cnt = 0;
        }
        const int4* u4 = (const int4*)usage;
        float4* o4 = (float4*)(out + OUT_USAGE);    // offset %4==0: 16B-aligned
        const int TOT4 = N_TOT / 4;                 // 125000
        for (int g = ub * 256 + tid; g < TOT4; g += USAGE_BLKS * 256) {
            int4 u = u4[g];
            o4[g] = make_float4((float)u.x, (float)u.y, (float)u.z, (float)u.w);
        }
    } else {
        // ---------------- row-copy role: LDS-staged; NONTEMPORAL loads -------------
        const int cb = b - (ARGMIN_BLKS + HIST_BLKS + USAGE_BLKS);  // 0..31249
        const int n0 = cb * CROWS;
        const f4v* src = (const f4v*)(mdesc + (size_t)n0 * 256);    // 1024 float4
#pragma unroll
        for (int it = 0; it < 4; it++) {
            int g = tid + it * 256;
            f4v v = __builtin_nontemporal_load(src + g);            // bypass L2 reuse
            int e = g * 4;
            int r = e >> 8;
            int c = e & 255;
            float* d = smem + r * 259 + 3 + c;
            d[0] = v.x; d[1] = v.y; d[2] = v.z; d[3] = v.w;
        }
        if (tid < CROWS * 3) {
            int r = tid / 3, c = tid - r * 3;
            smem[r * 259 + c] = mpts[(size_t)n0 * 3 + tid];
        }
        __syncthreads();

        float4* dst4 = (float4*)(out + (size_t)cb * TILE_F);
        const float4* s4 = (const float4*)smem;
#pragma unroll
        for (int it = 0; it < 5; it++) {
            int g = tid + it * 256;
            if (g < TILE_F / 4) dst4[g] = s4[g];
        }
    }
}

// ============  TAIL (one kernel): scanV -> collect(64) -> final  ===================
__global__ __launch_bounds__(256) void k_tail(
    const float* __restrict__ pts, const int* __restrict__ usage,
    const float* __restrict__ partKey, const int* __restrict__ partIdx,
    const int* __restrict__ histPart, int* __restrict__ Vp, int* __restrict__ cnt,
    int* __restrict__ flags, unsigned* __restrict__ keysG, float* __restrict__ out)
{
    __shared__ int smem[4400];            // keys[4096] | sc[256] | misc
    unsigned* keys = (unsigned*)smem;
    int* sc     = smem + 4096;
    int* s_misc = smem + 4352;
    const int b = blockIdx.x, tid = threadIdx.x;

    if (b == 0) {
        // ---------------- scanV: total hist (4 bins/thread), scan, cutoff V --------
        int h[4];
#pragma unroll
        for (int j = 0; j < 4; j++) {
            h[j] = 0;
            for (int bb = 0; bb < HIST_BLKS; bb++) h[j] += histPart[bb * 1024 + tid * 4 + j];
        }
        int lsum = h[0] + h[1] + h[2] + h[3];
        sc[tid] = lsum; __syncthreads();
        for (int off = 1; off < 256; off <<= 1) {
            int add = (tid >= off) ? sc[tid - off] : 0;
            __syncthreads();
            sc[tid] += add;
            __syncthreads();
        }
        int run = sc[tid] - lsum;             // exclusive count(usage < 4*tid)
#pragma unroll
        for (int j = 0; j < 4; j++) {
            int incl = run + h[j];
            if (run < M_Q && incl >= M_Q) atomicExch(Vp, tid * 4 + j);  // unique bin
            run = incl;
        }
        __syncthreads();
        if (tid == 0) { __threadfence(); atomicAdd(&flags[F_SCN], 1); }

        // ---------------- final: wait collect, sort, rank, outputs -----------------
        if (tid == 0) {
            spin_until(&flags[F_COL], COLL_BLKS);
            s_misc[0] = atomicAdd(cnt, 0);
        }
        __syncthreads();
        int C = s_misc[0]; if (C > CAND_MAX) C = CAND_MAX;
        int P2 = 1; while (P2 < C) P2 <<= 1;

        // per-thread 4 queries: reduce NSPLIT partials (ascending order: strict <)
        int bi4[4], msk[4];
#pragma unroll
        for (int j = 0; j < 4; j++) {
            int q = tid * 4 + j;
            float bk = INFINITY; int ix = 0x7fffffff;
            for (int s = 0; s < NSPLIT; s++) {
                float k = partKey[q * NSPLIT + s];
                int   i = partIdx[q * NSPLIT + s];
                if (k < bk) { bk = k; ix = i; }
            }
            float px = pts[3*q], py = pts[3*q+1], pz = pts[3*q+2];
            float d2 = px*px + py*py + pz*pz + 2.0f * bk;
            msk[j] = (d2 > 1e-6f) ? 1 : 0;    // sqrt(max(d2,1e-12)) > 1e-3
            bi4[j] = ix;
        }

        for (int p = tid; p < P2; p += 256) keys[p] = (p < C) ? keysG[p] : 0xFFFFFFFFu;
        __syncthreads();

        // bitonic sort ascending -> (usage asc, index asc) == lax.top_k order
        for (int k2 = 2; k2 <= P2; k2 <<= 1) {
            for (int j = k2 >> 1; j > 0; j >>= 1) {
                for (int i = tid; i < P2; i += 256) {
                    int ixj = i ^ j;
                    if (ixj > i) {
                        unsigned a = keys[i], bb2 = keys[ixj];
                        bool up = ((i & k2) == 0);
                        if ((a > bb2) == up) { keys[i] = bb2; keys[ixj] = a; }
                    }
                }
                __syncthreads();
            }
        }

        // rank = cumsum(mask)-1 over queries in order
        int lsum2 = msk[0] + msk[1] + msk[2] + msk[3];
        sc[tid] = lsum2; __syncthreads();
        for (int off = 1; off < 256; off <<= 1) {
            int add = (tid >= off) ? sc[tid - off] : 0;
            __syncthreads();
            sc[tid] += add;
            __syncthreads();
        }
        int run2 = sc[tid] - lsum2;
#pragma unroll
        for (int j = 0; j < 4; j++) {
            int q = tid * 4 + j;
            run2 += msk[j];
            int idx = msk[j] ? (int)(keys[run2 - 1] & 0x7FFFFu) : bi4[j];
            out[(size_t)OUT_IDX + (size_t)q] = (float)idx;
            atomicAdd(out + OUT_USAGE + idx, 1.0f);   // base usage written by mega
        }
    } else {
        // ---------------- collect role: candidates usage <= V, unordered -----------
        const int rb = b - 1;                 // 0..63
        if (tid == 0) {
            spin_until(&flags[F_SCN], 1);
            s_misc[0] = atomicAdd(Vp, 0);
        }
        __syncthreads();
        const int V = s_misc[0];
        for (int n = rb * 256 + tid; n < N_TOT; n += COLL_BLKS * 256) {
            int u = usage[n];
            if (u <= V) {
                int p = atomicAdd(cnt, 1);
                if (p < CAND_MAX) keysG[p] = ((unsigned)u << 19) | (unsigned)n;
            }
        }
        __threadfence();
        __syncthreads();
        if (tid == 0) atomicAdd(&flags[F_COL], 1);
    }
}

extern "C" void kernel_launch(void* const* d_in, const int* in_sizes, int n_in,
                              void* d_out, int out_size, void* d_ws, size_t ws_size,
                              hipStream_t stream)
{
    (void)in_sizes; (void)n_in; (void)out_size; (void)ws_size;
    const float* pts   = (const float*)d_in[0];
    const float* mpts  = (const float*)d_in[2];
    const float* mdesc = (const float*)d_in[3];
    const int*   usage = (const int*)d_in[4];
    float* out = (float*)d_out;

    char* ws = (char*)d_ws;
    float*    partKey  = (float*)(ws + WS_PARTKEY);
    int*      partIdx  = (int*)(ws + WS_PARTIDX);
    int*      histPart = (int*)(ws + WS_HISTP);
    int*      Vp       = (int*)(ws + WS_V);
    int*      cnt      = (int*)(ws + WS_CNT);
    int*      flags    = (int*)(ws + WS_FLAGS);
    unsigned* keysG    = (unsigned*)(ws + WS_KEYS);

    k_mega<<<MEGA_BLKS, 256, 0, stream>>>(pts, mpts, mdesc, usage, out,
                                          partKey, partIdx, histPart, flags, cnt);
    k_tail<<<TAIL_BLKS, 256, 0, stream>>>(pts, usage, partKey, partIdx, histPart,
                                          Vp, cnt, flags, keysG, out);
}

// Round 12
// 332.995 us; speedup vs baseline: 1.5411x; 1.1257x over previous
//
#include <hip/hip_runtime.h>

#define N_TOT   500000
#define M_Q     1024
#define QB      16
#define NSPLIT  16
#define CAND_MAX 8192

#define ARGMIN_BLKS 1024            // 64 query-tiles x 16 N-splits
#define HIST_BLKS   32
#define USAGE_BLKS  64
#define CROWS       16              // rows per copy tile
#define COPY_BLKS   (N_TOT / CROWS) // 31250
#define MEGA_BLKS   (ARGMIN_BLKS + HIST_BLKS + USAGE_BLKS + COPY_BLKS)
#define HIST_CHUNK  (N_TOT / HIST_BLKS)   // 15625
#define TILE_F      (CROWS * 259)         // 4144 floats (16B-aligned)

static const unsigned OUT_ROWS  = 259u * (unsigned)N_TOT;     // 129,500,000
static const unsigned OUT_USAGE = OUT_ROWS;
static const unsigned OUT_IDX   = OUT_ROWS + (unsigned)N_TOT; // 130,000,000

// ---- ws layout (bytes) ----
#define WS_PARTKEY 0                 // M*NSPLIT f32 = 65536
#define WS_PARTIDX 65536             // M*NSPLIT i32 = 65536
#define WS_HISTP   131072            // 32*1024 i32  = 131072 (plain stores, no zeroing)
#define WS_V       262144            // 1 i32
#define WS_CNT     262148            // 1 i32
#define WS_KEYS    262152            // CAND_MAX u32 = 32768

typedef float f4v __attribute__((ext_vector_type(4)));

// =====================  MEGA: argmin || hist || usage-copy || row-copy ==============
// R4 champion, single change: copy-role mdesc loads are NONTEMPORAL (R11 win).
__global__ __launch_bounds__(256) void k_mega(
    const float* __restrict__ pts,  const float* __restrict__ mpts,
    const float* __restrict__ mdesc, const int* __restrict__ usage,
    float* __restrict__ out,
    float* __restrict__ partKey, int* __restrict__ partIdx,
    int* __restrict__ histPart)
{
    __shared__ float smem[TILE_F];        // 16576 B, unioned across roles
    const int b   = blockIdx.x;
    const int tid = threadIdx.x;

    if (b < ARGMIN_BLKS) {
        // ---------------- argmin role (math identical since R1: absmax 0) ----------
        const int qb = b & 63;
        const int ns = b >> 6;
        const int qbase = qb * QB;
        const int chunk = N_TOT / NSPLIT;   // 31250
        const int n0 = ns * chunk;
        const int n1 = n0 + chunk;

        float* qs = smem;                   // 48 floats
        float* wk = smem + 64;              // [4][16]
        int*   wi = (int*)(smem + 192);     // [4][16]
        if (tid < QB * 3) qs[tid] = pts[qbase * 3 + tid];
        __syncthreads();

        float qx[QB], qy[QB], qz[QB];
#pragma unroll
        for (int i = 0; i < QB; i++) { qx[i] = qs[3*i]; qy[i] = qs[3*i+1]; qz[i] = qs[3*i+2]; }

        float bk[QB]; int bi[QB];
#pragma unroll
        for (int i = 0; i < QB; i++) { bk[i] = INFINITY; bi[i] = 0x7fffffff; }

        for (int n = n0 + tid; n < n1; n += 256) {
            float x = mpts[3*n+0], y = mpts[3*n+1], z = mpts[3*n+2];
            float h = 0.5f * (x*x + y*y + z*z);
#pragma unroll
            for (int i = 0; i < QB; i++) {
                float key = h - x*qx[i] - y*qy[i] - z*qz[i];
                bool lt = key < bk[i];      // strict < + ascending n => first-min kept
                bk[i] = lt ? key : bk[i];
                bi[i] = lt ? n   : bi[i];
            }
        }

        const int lane = tid & 63;
        const int wv   = tid >> 6;
#pragma unroll
        for (int off = 32; off > 0; off >>= 1) {
#pragma unroll
            for (int i = 0; i < QB; i++) {
                float ok = __shfl_down(bk[i], off, 64);
                int   oi = __shfl_down(bi[i], off, 64);
                if (ok < bk[i] || (ok == bk[i] && oi < bi[i])) { bk[i] = ok; bi[i] = oi; }
            }
        }
        if (lane == 0) {
#pragma unroll
            for (int i = 0; i < QB; i++) { wk[wv*QB + i] = bk[i]; wi[wv*QB + i] = bi[i]; }
        }
        __syncthreads();
        if (tid < QB) {
            float k = wk[tid]; int ix = wi[tid];
#pragma unroll
            for (int w = 1; w < 4; w++) {
                float ok = wk[w*QB + tid]; int oi = wi[w*QB + tid];
                if (ok < k || (ok == k && oi < ix)) { k = ok; ix = oi; }
            }
            partKey[(qbase + tid) * NSPLIT + ns] = k;
            partIdx[(qbase + tid) * NSPLIT + ns] = ix;
        }
    } else if (b < ARGMIN_BLKS + HIST_BLKS) {
        // ---------------- hist role: per-block partial histogram -------------------
        const int hb = b - ARGMIN_BLKS;
        const int r0 = hb * HIST_CHUNK;
        const int r1 = r0 + HIST_CHUNK;
        int* lh = (int*)smem;
#pragma unroll
        for (int i = 0; i < 4; i++) lh[tid + i * 256] = 0;
        __syncthreads();
        for (int n = r0 + tid; n < r1; n += 256) {
            unsigned v = (unsigned)usage[n];
            if (v > 1023u) v = 1023u;
            atomicAdd(&lh[v], 1);
        }
        __syncthreads();
#pragma unroll
        for (int i = 0; i < 4; i++) {
            int bin = tid + i * 256;
            histPart[hb * 1024 + bin] = lh[bin];
        }
    } else if (b < ARGMIN_BLKS + HIST_BLKS + USAGE_BLKS) {
        // ---------------- usage-as-float role (int4 -> float4) ---------------------
        const int ub = b - ARGMIN_BLKS - HIST_BLKS;
        const int4* u4 = (const int4*)usage;
        float4* o4 = (float4*)(out + OUT_USAGE);    // offset %4==0: 16B-aligned
        const int TOT4 = N_TOT / 4;                 // 125000
        for (int g = ub * 256 + tid; g < TOT4; g += USAGE_BLKS * 256) {
            int4 u = u4[g];
            o4[g] = make_float4((float)u.x, (float)u.y, (float)u.z, (float)u.w);
        }
    } else {
        // ---------------- row-copy role: LDS-staged, NONTEMPORAL loads -------------
        const int cb = b - (ARGMIN_BLKS + HIST_BLKS + USAGE_BLKS);  // 0..31249
        const int n0 = cb * CROWS;
        const f4v* src = (const f4v*)(mdesc + (size_t)n0 * 256);    // 1024 float4
#pragma unroll
        for (int it = 0; it < 4; it++) {
            int g = tid + it * 256;           // 0..1023 float4s
            f4v v = __builtin_nontemporal_load(src + g);
            int e = g * 4;
            int r = e >> 8;
            int c = e & 255;
            float* d = smem + r * 259 + 3 + c;
            d[0] = v.x; d[1] = v.y; d[2] = v.z; d[3] = v.w;
        }
        if (tid < CROWS * 3) {
            int r = tid / 3, c = tid - r * 3;
            smem[r * 259 + c] = mpts[(size_t)n0 * 3 + tid];
        }
        __syncthreads();

        // store contiguous tile span: 1036 aligned float4s
        float4* dst4 = (float4*)(out + (size_t)cb * TILE_F);
        const float4* s4 = (const float4*)smem;
#pragma unroll
        for (int it = 0; it < 5; it++) {
            int g = tid + it * 256;
            if (g < TILE_F / 4) dst4[g] = s4[g];
        }
    }
}

// =====================  scanV: total hist, scan, cutoff V, zero cnt  ===============
__global__ __launch_bounds__(1024) void k_scanV(
    const int* __restrict__ histPart, int* __restrict__ Vout, int* __restrict__ cnt)
{
    __shared__ int scan[1024];
    const int t = threadIdx.x;
    int h = 0;
#pragma unroll
    for (int b = 0; b < HIST_BLKS; b++) h += histPart[b * 1024 + t];
    scan[t] = h; __syncthreads();
    for (int off = 1; off < 1024; off <<= 1) {
        int add = (t >= off) ? scan[t - off] : 0;
        __syncthreads();
        scan[t] += add;
        __syncthreads();
    }
    int cum  = scan[t] - h;    // count(usage < t)
    int cumN = scan[t];        // count(usage <= t)
    if (cum < M_Q && cumN >= M_Q) { *Vout = t; *cnt = 0; }
}

// =====================  collect candidates (usage <= V), unordered  ================
__global__ __launch_bounds__(256) void k_collect(
    const int* __restrict__ usage, const int* __restrict__ Vp,
    int* __restrict__ cnt, unsigned* __restrict__ keys)
{
    const int V = *Vp;
    const int stride = gridDim.x * 256;
    for (int n = blockIdx.x * 256 + threadIdx.x; n < N_TOT; n += stride) {
        int u = usage[n];
        if (u <= V) {
            int p = atomicAdd(cnt, 1);
            if (p < CAND_MAX) keys[p] = ((unsigned)u << 19) | (unsigned)n;
        }
    }
}

// =====================  final: sort, rank, idx out, usage bump  ====================
__global__ __launch_bounds__(1024) void k_final(
    const float* __restrict__ pts,
    const float* __restrict__ partKey, const int* __restrict__ partIdx,
    const int* __restrict__ cntP, const unsigned* __restrict__ keysG,
    float* __restrict__ out)
{
    __shared__ unsigned keys[CAND_MAX];
    __shared__ int      mscan[1024];
    const int t = threadIdx.x;

    // 1) reduce NSPLIT partials (ascending-n chunk order: strict <)
    float bk = INFINITY; int bi = 0x7fffffff;
#pragma unroll
    for (int s = 0; s < NSPLIT; s++) {
        float k = partKey[t * NSPLIT + s];
        int   i = partIdx[t * NSPLIT + s];
        if (k < bk) { bk = k; bi = i; }
    }
    float px = pts[3*t], py = pts[3*t+1], pz = pts[3*t+2];
    float d2 = px*px + py*py + pz*pz + 2.0f * bk;
    const bool mask = d2 > 1e-6f;   // sqrt(max(d2,1e-12)) > 1e-3

    // 2) load candidates, pad to next pow2 (C >= M_Q by construction of V)
    int C = *cntP; if (C > CAND_MAX) C = CAND_MAX;
    int P2 = 1; while (P2 < C) P2 <<= 1;
    for (int p = t; p < P2; p += 1024) keys[p] = (p < C) ? keysG[p] : 0xFFFFFFFFu;
    __syncthreads();

    // 3) bitonic sort ascending -> (usage asc, index asc) == lax.top_k order
    for (int k = 2; k <= P2; k <<= 1) {
        for (int j = k >> 1; j > 0; j >>= 1) {
            for (int i = t; i < P2; i += 1024) {
                int ixj = i ^ j;
                if (ixj > i) {
                    unsigned a = keys[i], bb = keys[ixj];
                    bool up = ((i & k) == 0);
                    if ((a > bb) == up) { keys[i] = bb; keys[ixj] = a; }
                }
            }
            __syncthreads();
        }
    }

    // 4) rank = cumsum(mask)-1 ; final idx; outputs
    mscan[t] = mask ? 1 : 0; __syncthreads();
    for (int off = 1; off < 1024; off <<= 1) {
        int add = (t >= off) ? mscan[t - off] : 0;
        __syncthreads();
        mscan[t] += add;
        __syncthreads();
    }
    int rank = mscan[t] - 1;
    int idx = mask ? (int)(keys[rank] & 0x7FFFFu) : bi;
    out[(size_t)OUT_IDX + (size_t)t] = (float)idx;
    atomicAdd(out + OUT_USAGE + idx, 1.0f);   // after mega wrote base usage
}

extern "C" void kernel_launch(void* const* d_in, const int* in_sizes, int n_in,
                              void* d_out, int out_size, void* d_ws, size_t ws_size,
                              hipStream_t stream)
{
    (void)in_sizes; (void)n_in; (void)out_size; (void)ws_size;
    const float* pts   = (const float*)d_in[0];
    const float* mpts  = (const float*)d_in[2];
    const float* mdesc = (const float*)d_in[3];
    const int*   usage = (const int*)d_in[4];
    float* out = (float*)d_out;

    char* ws = (char*)d_ws;
    float*    partKey  = (float*)(ws + WS_PARTKEY);
    int*      partIdx  = (int*)(ws + WS_PARTIDX);
    int*      histPart = (int*)(ws + WS_HISTP);
    int*      Vp       = (int*)(ws + WS_V);
    int*      cnt      = (int*)(ws + WS_CNT);
    unsigned* keys     = (unsigned*)(ws + WS_KEYS);

    k_mega<<<MEGA_BLKS, 256, 0, stream>>>(pts, mpts, mdesc, usage, out,
                                          partKey, partIdx, histPart);
    k_scanV<<<1, 1024, 0, stream>>>(histPart, Vp, cnt);
    k_collect<<<64, 256, 0, stream>>>(usage, Vp, cnt, keys);
    k_final<<<1, 1024, 0, stream>>>(pts, partKey, partIdx, cnt, keys, out);
}